// Round 8
// baseline (887.991 us; speedup 1.0000x reference)
//
#include <hip/hip_runtime.h>

#define N_NODES  50000
#define R_REL    3
#define E_EDGES  50000
#define EP_EDGES 100000
#define ELL_CAP  32

typedef __attribute__((ext_vector_type(8))) short  short8;
typedef __attribute__((ext_vector_type(8))) unsigned short ushort8;
typedef __attribute__((ext_vector_type(4))) float  floatx4;

static inline int cdiv_h(int a, int b) { return (a + b - 1) / b; }

__device__ inline unsigned short f2b(float f) {
    union { float f; unsigned u; } v; v.f = f;
    return (unsigned short)((v.u + 0x7FFF + ((v.u >> 16) & 1)) >> 16);
}
__device__ inline float b2f(unsigned short h) {
    union { unsigned u; float f; } v; v.u = ((unsigned)h) << 16;
    return v.f;
}

// ---------------- degree count + ELL fill ----------------
__global__ void count_fill_kernel(const int* __restrict__ src, const int* __restrict__ dst,
                                  int* __restrict__ outcnt, int* __restrict__ incnt,
                                  int* __restrict__ ell) {
    int i = blockIdx.x * blockDim.x + threadIdx.x;
    if (i >= R_REL * E_EDGES) return;
    int r = i / E_EDGES;
    int s = src[i], d = dst[i];
    atomicAdd(&outcnt[r * N_NODES + s], 1);
    int k = atomicAdd(&incnt[r * N_NODES + d], 1);
    if (k < ELL_CAP)
        ell[((size_t)(r * N_NODES + d) << 5) + k] = s;
}

__global__ void norm_kernel(const int* __restrict__ cnt, float* __restrict__ nrm, int n) {
    int i = blockIdx.x * blockDim.x + threadIdx.x;
    if (i < n) nrm[i] = rsqrtf(fmaxf((float)cnt[i], 1.0f));
}

// ---------------- fp32 -> bf16 (8 elems/thread) ----------------
__global__ void f2b8_kernel(const float* __restrict__ in, unsigned short* __restrict__ out,
                            int total8) {
    int i = blockIdx.x * blockDim.x + threadIdx.x;
    if (i >= total8) return;
    float4 a = ((const float4*)in)[2 * i];
    float4 b = ((const float4*)in)[2 * i + 1];
    ushort8 o;
    o[0] = f2b(a.x); o[1] = f2b(a.y); o[2] = f2b(a.z); o[3] = f2b(a.w);
    o[4] = f2b(b.x); o[5] = f2b(b.y); o[6] = f2b(b.z); o[7] = f2b(b.w);
    ((ushort8*)out)[i] = o;
}

// ---------------- W[r][k][n] fp32 -> Bt_all[r*dout+n][k] bf16, zero-pad rows >= 3*dout ----
__global__ void wcvt_kernel(const float* __restrict__ W, unsigned short* __restrict__ Wt,
                            int K, int dout, int total) {
    int i = blockIdx.x * blockDim.x + threadIdx.x;
    if (i >= total) return;
    int k = i % K;
    int nall = i / K;
    int r = nall / dout;
    int n = nall - r * dout;
    Wt[i] = (r < R_REL) ? f2b(W[((size_t)r * K + k) * dout + n]) : (unsigned short)0;
}

// ---------------- Wp1[128][64] fp32 -> But[128][64] bf16 ----------------
__global__ void wp1cvt_kernel(const float* __restrict__ Wp1, unsigned short* __restrict__ But) {
    int i = blockIdx.x * blockDim.x + threadIdx.x;
    if (i >= 128 * 64) return;
    int k = i & 63;
    int jo = i >> 6;
    int j = jo & 63;
    int half = jo >> 6;
    But[i] = f2b(Wp1[(size_t)(half * 64 + k) * 64 + j]);
}

// ---------------- fused MFMA GEMM: C[m][n] = (A[m][:].Bt[n][:]) * sn[n/dout][m] --------
// BM=128 BN=128, 256 thr (4 waves; wm=w&1 -> 64-row half, wn=w>>1 -> 64-col half;
// wave tile 64x64 = 4x4 16x16 tiles, 64-reg acc).
// NO LDS, NO barriers: each wave loads its own A/B fragments global->VGPR with a
// depth-2 register pipeline; waits are per-wave s_waitcnt vmcnt(N) only.
// K%64==0, NdPad%128==0. sn==nullptr -> scale 1 (and no relation guard).
// XCD-locality swizzle: blocks p==j (mod 8) share one m-panel across all n-blocks.
__global__ __launch_bounds__(256) void gemm_bf16_fused(
        const unsigned short* __restrict__ A, const unsigned short* __restrict__ Bt,
        unsigned short* __restrict__ C, const float* __restrict__ sn,
        int M, int K, int NdPad, int dout) {
    const int nN = gridDim.x, nM = gridDim.y;
    int p = blockIdx.y * nN + blockIdx.x;
    const int nig = nN << 3;
    int group = p / nig;
    int rem = p - group * nig;
    int gs = nM - (group << 3); if (gs > 8) gs = 8;
    int mb = (group << 3) + rem % gs;
    int nb = rem / gs;
    const int m0 = mb * 128, n0 = nb * 128;

    const int tid  = threadIdx.x;
    const int w    = tid >> 6;
    const int lane = tid & 63;
    const int wm   = w & 1;          // 64-row half
    const int wn   = w >> 1;         // 64-col half
    const int mrow = lane & 15;
    const int ko   = (lane >> 4) * 8;

    const unsigned short* abase = A  + (size_t)(m0 + wm * 64 + mrow) * K + ko;
    const unsigned short* bbase = Bt + (size_t)(n0 + wn * 64 + mrow) * K + ko;

    floatx4 acc[4][4];
#pragma unroll
    for (int i = 0; i < 4; ++i)
#pragma unroll
        for (int j = 0; j < 4; ++j) acc[i][j] = (floatx4){0.f, 0.f, 0.f, 0.f};

    short8 af[2][4], bf[2][4];
    const int nsteps = K >> 5;       // always even (K % 64 == 0)

    // prologue: fill both pipeline slots (steps 0 and 1)
#pragma unroll
    for (int t = 0; t < 4; ++t) {
        af[0][t] = *(const short8*)(abase + (size_t)t * 16 * K);
        bf[0][t] = *(const short8*)(bbase + (size_t)t * 16 * K);
    }
#pragma unroll
    for (int t = 0; t < 4; ++t) {
        af[1][t] = *(const short8*)(abase + (size_t)t * 16 * K + 32);
        bf[1][t] = *(const short8*)(bbase + (size_t)t * 16 * K + 32);
    }

    for (int s = 0; s < nsteps; s += 2) {
        // slot 0: compute step s, refill with step s+2
#pragma unroll
        for (int mt = 0; mt < 4; ++mt)
#pragma unroll
            for (int nt = 0; nt < 4; ++nt)
                acc[mt][nt] = __builtin_amdgcn_mfma_f32_16x16x32_bf16(af[0][mt], bf[0][nt],
                                                                      acc[mt][nt], 0, 0, 0);
        if (s + 2 < nsteps) {
            int kk = (s + 2) << 5;
#pragma unroll
            for (int t = 0; t < 4; ++t) {
                af[0][t] = *(const short8*)(abase + (size_t)t * 16 * K + kk);
                bf[0][t] = *(const short8*)(bbase + (size_t)t * 16 * K + kk);
            }
        }
        // slot 1: compute step s+1, refill with step s+3
#pragma unroll
        for (int mt = 0; mt < 4; ++mt)
#pragma unroll
            for (int nt = 0; nt < 4; ++nt)
                acc[mt][nt] = __builtin_amdgcn_mfma_f32_16x16x32_bf16(af[1][mt], bf[1][nt],
                                                                      acc[mt][nt], 0, 0, 0);
        if (s + 3 < nsteps) {
            int kk = (s + 3) << 5;
#pragma unroll
            for (int t = 0; t < 4; ++t) {
                af[1][t] = *(const short8*)(abase + (size_t)t * 16 * K + kk);
                bf[1][t] = *(const short8*)(bbase + (size_t)t * 16 * K + kk);
            }
        }
    }

    // epilogue: C/D layout col=lane&15, row=(lane>>4)*4+reg
    const int colb = n0 + wn * 64;
    const int r_quad = colb / dout;          // relation of this 64-col quadrant
    if (sn && r_quad >= R_REL) return;       // zero-pad columns: skip store
    const int col = colb + (lane & 15);
    const int rb0 = m0 + wm * 64 + (lane >> 4) * 4;
#pragma unroll
    for (int mt = 0; mt < 4; ++mt) {
#pragma unroll
        for (int reg = 0; reg < 4; ++reg) {
            int row = rb0 + mt * 16 + reg;
            if (row < M) {
                float rs = sn ? sn[(size_t)r_quad * N_NODES + row] : 1.0f;
#pragma unroll
                for (int nt = 0; nt < 4; ++nt)
                    C[(size_t)row * NdPad + col + nt * 16] = f2b(acc[mt][nt][reg] * rs);
            }
        }
    }
}

// ---------------- fused 3-relation ELL gather + bias-sum + optional ReLU ----------------
// hr rows are [rel0 | rel1 | rel2 | pad] with row stride S8 ushort8-chunks.
__global__ void gather3_kernel(const unsigned short* __restrict__ hr, int S8, int d8,
                               const int* __restrict__ ell, const int* __restrict__ incnt,
                               const float* __restrict__ dn, const float* __restrict__ bias,
                               unsigned short* __restrict__ outh,
                               int lgc, int total, int do_relu, int dout) {
    int i = blockIdx.x * blockDim.x + threadIdx.x;
    if (i >= total) return;
    int d = i >> lgc;
    int c = i & ((1 << lgc) - 1);
    float acc[8] = {0.f, 0.f, 0.f, 0.f, 0.f, 0.f, 0.f, 0.f};
    const ushort8* hr8 = (const ushort8*)hr;
#pragma unroll
    for (int r = 0; r < R_REL; ++r) {
        int nr = incnt[r * N_NODES + d];
        nr = nr < ELL_CAP ? nr : ELL_CAP;
        size_t base = (size_t)(r * N_NODES + d) << 5;
        float a[8] = {0.f, 0.f, 0.f, 0.f, 0.f, 0.f, 0.f, 0.f};
        for (int k = 0; k < nr; ++k) {
            int s = ell[base + k];
            ushort8 v = hr8[(size_t)s * S8 + r * d8 + c];
#pragma unroll
            for (int j = 0; j < 8; ++j) a[j] += b2f(v[j]);
        }
        float dnd = dn[r * N_NODES + d];
#pragma unroll
        for (int j = 0; j < 8; ++j) acc[j] += dnd * a[j];
    }
    int f = c << 3;
#pragma unroll
    for (int j = 0; j < 8; ++j)
        acc[j] += bias[f + j] + bias[dout + f + j] + bias[2 * dout + f + j];
    if (do_relu) {
#pragma unroll
        for (int j = 0; j < 8; ++j) acc[j] = fmaxf(acc[j], 0.f);
    }
    ushort8 o;
#pragma unroll
    for (int j = 0; j < 8; ++j) o[j] = f2b(acc[j]);
    ((ushort8*)outh)[i] = o;
}

// ---------------- edge scores from UV: score = Wp2 . relu(U[s]+V[d]+bp1) + bp2 ----------
__global__ __launch_bounds__(256) void edge_score_kernel(
        const unsigned short* __restrict__ UV,
        const int* __restrict__ pos_src, const int* __restrict__ pos_dst,
        const int* __restrict__ neg_src, const int* __restrict__ neg_dst,
        const float* __restrict__ bp1, const float* __restrict__ Wp2,
        const float* __restrict__ bp2, float* __restrict__ outp) {
    __shared__ float sb[64], sw[64];
    int t = threadIdx.x;
    if (t < 64) { sb[t] = bp1[t]; sw[t] = Wp2[t]; }
    __syncthreads();
    int i = blockIdx.x * blockDim.x + t;
    if (i >= 2 * EP_EDGES) return;
    int s, d;
    if (i < EP_EDGES) { s = pos_src[i]; d = pos_dst[i]; }
    else              { s = neg_src[i - EP_EDGES]; d = neg_dst[i - EP_EDGES]; }
    const ushort8* UV8 = (const ushort8*)UV;
    float acc = bp2[0];
#pragma unroll
    for (int jv = 0; jv < 8; ++jv) {
        ushort8 u = UV8[(size_t)s * 16 + jv];
        ushort8 v = UV8[(size_t)d * 16 + 8 + jv];
#pragma unroll
        for (int j = 0; j < 8; ++j) {
            float z = b2f(u[j]) + b2f(v[j]) + sb[jv * 8 + j];
            acc = fmaf(fmaxf(z, 0.f), sw[jv * 8 + j], acc);
        }
    }
    outp[i] = acc;
}

extern "C" void kernel_launch(void* const* d_in, const int* in_sizes, int n_in,
                              void* d_out, int out_size, void* d_ws, size_t ws_size,
                              hipStream_t stream) {
    const float* x       = (const float*)d_in[0];
    const int*   rel_src = (const int*)d_in[1];
    const int*   rel_dst = (const int*)d_in[2];
    const int*   pos_src = (const int*)d_in[3];
    const int*   pos_dst = (const int*)d_in[4];
    const int*   neg_src = (const int*)d_in[5];
    const int*   neg_dst = (const int*)d_in[6];
    const float* W[4]    = {(const float*)d_in[7],  (const float*)d_in[9],
                            (const float*)d_in[11], (const float*)d_in[13]};
    const float* bias[4] = {(const float*)d_in[8],  (const float*)d_in[10],
                            (const float*)d_in[12], (const float*)d_in[14]};
    const float* Wp1 = (const float*)d_in[15];
    const float* bp1 = (const float*)d_in[16];
    const float* Wp2 = (const float*)d_in[17];
    const float* bp2 = (const float*)d_in[18];
    float* out = (float*)d_out;

    // workspace layout (bf16 buffers padded +128 rows for OOB tile reads, BM=128)
    size_t NP = (size_t)(N_NODES + 128);
    unsigned short* xb  = (unsigned short*)d_ws;          // NP x 512 (reused for UV later)
    unsigned short* h0  = xb + NP * 512;                  // NP x 512
    unsigned short* h1  = h0 + NP * 512;                  // NP x 256
    unsigned short* hr  = h1 + NP * 256;                  // N x 1536 max (fused C)
    unsigned short* Wt  = hr + (size_t)R_REL * N_NODES * 512;   // 1536*512 max
    unsigned short* But = Wt + (size_t)R_REL * 512 * 512;       // 128*64
    float* sn   = (float*)(But + 128 * 64);
    float* dn   = sn + (size_t)R_REL * N_NODES;
    int* outcnt = (int*)(dn + (size_t)R_REL * N_NODES);
    int* incnt  = outcnt + (size_t)R_REL * N_NODES;
    int* ell    = incnt + (size_t)R_REL * N_NODES;        // 3*N*32 ints
    unsigned short* UV = xb;                              // N x 128 (after layers done)

    hipMemsetAsync(outcnt, 0, sizeof(int) * 2 * R_REL * N_NODES, stream);
    count_fill_kernel<<<cdiv_h(R_REL * E_EDGES, 256), 256, 0, stream>>>(
        rel_src, rel_dst, outcnt, incnt, ell);
    norm_kernel<<<cdiv_h(R_REL * N_NODES, 256), 256, 0, stream>>>(outcnt, sn, R_REL * N_NODES);
    norm_kernel<<<cdiv_h(R_REL * N_NODES, 256), 256, 0, stream>>>(incnt, dn, R_REL * N_NODES);

    f2b8_kernel<<<cdiv_h(N_NODES * 512 / 8, 256), 256, 0, stream>>>(x, xb, N_NODES * 512 / 8);
    wp1cvt_kernel<<<cdiv_h(128 * 64, 256), 256, 0, stream>>>(Wp1, But);

    const int dims[5]  = {512, 512, 256, 128, 64};
    const int ndpad[4] = {1536, 768, 384, 256};   // 3*dout padded to x128
    unsigned short* hbufs[4] = {h0, h1, h0, h1};
    const unsigned short* hcur = xb;
    for (int l = 0; l < 4; ++l) {
        int din = dims[l], dout = dims[l + 1], NdPad = ndpad[l];
        unsigned short* hnext = hbufs[l];
        int wtot = NdPad * din;
        wcvt_kernel<<<cdiv_h(wtot, 256), 256, 0, stream>>>(W[l], Wt, din, dout, wtot);
        dim3 grid(NdPad / 128, cdiv_h(N_NODES, 128));
        gemm_bf16_fused<<<grid, 256, 0, stream>>>(hcur, Wt, hr, sn, N_NODES, din, NdPad, dout);
        int lgc = (dout == 512) ? 6 : (dout == 256) ? 5 : (dout == 128) ? 4 : 3; // log2(dout/8)
        int total = N_NODES << lgc;
        gather3_kernel<<<cdiv_h(total, 256), 256, 0, stream>>>(
            hr, NdPad / 8, dout / 8, ell, incnt, dn, bias[l], hnext, lgc, total,
            (l < 3) ? 1 : 0, dout);
        hcur = hnext;
    }

    // UV = h_final @ [Wp1_top | Wp1_bot]  (M=N, K=64, Nd=128)
    dim3 uvgrid(1, cdiv_h(N_NODES, 128));
    gemm_bf16_fused<<<uvgrid, 256, 0, stream>>>(hcur, But, UV, nullptr, N_NODES, 64, 128, 128);

    edge_score_kernel<<<cdiv_h(2 * EP_EDGES, 256), 256, 0, stream>>>(
        UV, pos_src, pos_dst, neg_src, neg_dst, bp1, Wp2, bp2, out);
}

// Round 9
// 618.406 us; speedup vs baseline: 1.4359x; 1.4359x over previous
//
#include <hip/hip_runtime.h>

#define N_NODES  50000
#define R_REL    3
#define E_EDGES  50000
#define EP_EDGES 100000
#define ELL_CAP  32

typedef __attribute__((ext_vector_type(8))) short  short8;
typedef __attribute__((ext_vector_type(8))) unsigned short ushort8;
typedef __attribute__((ext_vector_type(4))) float  floatx4;

static inline int cdiv_h(int a, int b) { return (a + b - 1) / b; }

__device__ inline unsigned short f2b(float f) {
    union { float f; unsigned u; } v; v.f = f;
    return (unsigned short)((v.u + 0x7FFF + ((v.u >> 16) & 1)) >> 16);
}
__device__ inline float b2f(unsigned short h) {
    union { unsigned u; float f; } v; v.u = ((unsigned)h) << 16;
    return v.f;
}

#define GLDS16(gp, lp) __builtin_amdgcn_global_load_lds( \
    (const __attribute__((address_space(1))) void*)(gp), \
    (__attribute__((address_space(3))) void*)(lp), 16, 0, 0)

// ---------------- degree count + ELL fill ----------------
__global__ void count_fill_kernel(const int* __restrict__ src, const int* __restrict__ dst,
                                  int* __restrict__ outcnt, int* __restrict__ incnt,
                                  int* __restrict__ ell) {
    int i = blockIdx.x * blockDim.x + threadIdx.x;
    if (i >= R_REL * E_EDGES) return;
    int r = i / E_EDGES;
    int s = src[i], d = dst[i];
    atomicAdd(&outcnt[r * N_NODES + s], 1);
    int k = atomicAdd(&incnt[r * N_NODES + d], 1);
    if (k < ELL_CAP)
        ell[((size_t)(r * N_NODES + d) << 5) + k] = s;
}

__global__ void norm_kernel(const int* __restrict__ cnt, float* __restrict__ nrm, int n) {
    int i = blockIdx.x * blockDim.x + threadIdx.x;
    if (i < n) nrm[i] = rsqrtf(fmaxf((float)cnt[i], 1.0f));
}

// ---------------- fp32 -> bf16 (8 elems/thread) ----------------
__global__ void f2b8_kernel(const float* __restrict__ in, unsigned short* __restrict__ out,
                            int total8) {
    int i = blockIdx.x * blockDim.x + threadIdx.x;
    if (i >= total8) return;
    float4 a = ((const float4*)in)[2 * i];
    float4 b = ((const float4*)in)[2 * i + 1];
    ushort8 o;
    o[0] = f2b(a.x); o[1] = f2b(a.y); o[2] = f2b(a.z); o[3] = f2b(a.w);
    o[4] = f2b(b.x); o[5] = f2b(b.y); o[6] = f2b(b.z); o[7] = f2b(b.w);
    ((ushort8*)out)[i] = o;
}

// ---------------- W[r][k][n] fp32 -> Bt_all[r*dout+n][k] bf16, zero-pad rows >= 3*dout ----
__global__ void wcvt_kernel(const float* __restrict__ W, unsigned short* __restrict__ Wt,
                            int K, int dout, int total) {
    int i = blockIdx.x * blockDim.x + threadIdx.x;
    if (i >= total) return;
    int k = i % K;
    int nall = i / K;
    int r = nall / dout;
    int n = nall - r * dout;
    Wt[i] = (r < R_REL) ? f2b(W[((size_t)r * K + k) * dout + n]) : (unsigned short)0;
}

// ---------------- Wp1[128][64] fp32 -> But[128][64] bf16 ----------------
__global__ void wp1cvt_kernel(const float* __restrict__ Wp1, unsigned short* __restrict__ But) {
    int i = blockIdx.x * blockDim.x + threadIdx.x;
    if (i >= 128 * 64) return;
    int k = i & 63;
    int jo = i >> 6;
    int j = jo & 63;
    int half = jo >> 6;
    But[i] = f2b(Wp1[(size_t)(half * 64 + k) * 64 + j]);
}

// ---------------- fused MFMA GEMM: C[m][n] = (A[m][:].Bt[n][:]) * sn[n/dout][m] --------
// R5 structure (best measured: L0=144us): BM=128 BN=128 BK=32, 256 thr, 4 waves,
// wave tile 64x64 = 4x4 16x16 tiles, A+B staged in LDS via global_load_lds, 2 barriers.
// + R6's verified XOR k-chunk swizzle (staging kc / read pA) -> 0 LDS bank conflicts.
// K%32==0, NdPad%128==0. sn==nullptr -> scale 1 (and no relation guard).
// XCD-locality swizzle: blocks p==j (mod 8) share one m-panel across all n-blocks.
__global__ __launch_bounds__(256) void gemm_bf16_fused(
        const unsigned short* __restrict__ A, const unsigned short* __restrict__ Bt,
        unsigned short* __restrict__ C, const float* __restrict__ sn,
        int M, int K, int NdPad, int dout) {
    __shared__ unsigned short As[4096];   // [128][32]
    __shared__ unsigned short Bs[4096];   // [128][32]

    const int nN = gridDim.x, nM = gridDim.y;
    int p = blockIdx.y * nN + blockIdx.x;
    const int nig = nN << 3;
    int group = p / nig;
    int rem = p - group * nig;
    int gs = nM - (group << 3); if (gs > 8) gs = 8;
    int mb = (group << 3) + rem % gs;
    int nb = rem / gs;
    const int m0 = mb * 128, n0 = nb * 128;

    const int tid  = threadIdx.x;
    const int w    = tid >> 6;
    const int lane = tid & 63;
    const int wm   = w & 1;          // 64-row half
    const int wn   = w >> 1;         // 64-col half
    const int lr   = lane >> 2;      // 0..15 staging row within 16-row chunk
    const int kc   = (((lane & 3) ^ ((lr >> 1) & 3)) << 3);  // swizzled global k-chunk (ushorts)

    floatx4 acc[4][4];
#pragma unroll
    for (int i = 0; i < 4; ++i)
#pragma unroll
        for (int j = 0; j < 4; ++j) acc[i][j] = (floatx4){0.f, 0.f, 0.f, 0.f};

    const int mrow = lane & 15;
    const int pA   = ((lane >> 4) ^ ((mrow >> 1) & 3)) << 3;  // swizzled LDS read k-offset

    for (int k0 = 0; k0 < K; k0 += 32) {
        // stage A tile (128 rows) and B tile (128 rows), 16B per lane, XOR-swizzled source
        GLDS16(A  + (size_t)(m0 +      w * 16 + lr) * K + k0 + kc, As +      w * 512);
        GLDS16(A  + (size_t)(m0 + 64 + w * 16 + lr) * K + k0 + kc, As + (4 + w) * 512);
        GLDS16(Bt + (size_t)(n0 +      w * 16 + lr) * K + k0 + kc, Bs +      w * 512);
        GLDS16(Bt + (size_t)(n0 + 64 + w * 16 + lr) * K + k0 + kc, Bs + (4 + w) * 512);
        __syncthreads();

        short8 a[4], b[4];
#pragma unroll
        for (int nt = 0; nt < 4; ++nt)
            b[nt] = *(const short8*)&Bs[(wn * 64 + nt * 16 + mrow) * 32 + pA];
#pragma unroll
        for (int mt = 0; mt < 4; ++mt)
            a[mt] = *(const short8*)&As[(wm * 64 + mt * 16 + mrow) * 32 + pA];
#pragma unroll
        for (int mt = 0; mt < 4; ++mt)
#pragma unroll
            for (int nt = 0; nt < 4; ++nt)
                acc[mt][nt] = __builtin_amdgcn_mfma_f32_16x16x32_bf16(a[mt], b[nt],
                                                                      acc[mt][nt], 0, 0, 0);
        __syncthreads();
    }

    // epilogue: C/D layout col=lane&15, row=(lane>>4)*4+reg
    const int colb = n0 + wn * 64;
    const int r_quad = colb / dout;          // relation of this 64-col quadrant
    if (sn && r_quad >= R_REL) return;       // zero-pad columns: skip store
    const int col = colb + (lane & 15);
    const int rb0 = m0 + wm * 64 + (lane >> 4) * 4;
#pragma unroll
    for (int mt = 0; mt < 4; ++mt) {
#pragma unroll
        for (int reg = 0; reg < 4; ++reg) {
            int row = rb0 + mt * 16 + reg;
            if (row < M) {
                float rs = sn ? sn[(size_t)r_quad * N_NODES + row] : 1.0f;
#pragma unroll
                for (int nt = 0; nt < 4; ++nt)
                    C[(size_t)row * NdPad + col + nt * 16] = f2b(acc[mt][nt][reg] * rs);
            }
        }
    }
}

// ---------------- fused 3-relation ELL gather + bias-sum + optional ReLU ----------------
// hr rows are [rel0 | rel1 | rel2 | pad] with row stride S8 ushort8-chunks.
__global__ void gather3_kernel(const unsigned short* __restrict__ hr, int S8, int d8,
                               const int* __restrict__ ell, const int* __restrict__ incnt,
                               const float* __restrict__ dn, const float* __restrict__ bias,
                               unsigned short* __restrict__ outh,
                               int lgc, int total, int do_relu, int dout) {
    int i = blockIdx.x * blockDim.x + threadIdx.x;
    if (i >= total) return;
    int d = i >> lgc;
    int c = i & ((1 << lgc) - 1);
    float acc[8] = {0.f, 0.f, 0.f, 0.f, 0.f, 0.f, 0.f, 0.f};
    const ushort8* hr8 = (const ushort8*)hr;
#pragma unroll
    for (int r = 0; r < R_REL; ++r) {
        int nr = incnt[r * N_NODES + d];
        nr = nr < ELL_CAP ? nr : ELL_CAP;
        size_t base = (size_t)(r * N_NODES + d) << 5;
        float a[8] = {0.f, 0.f, 0.f, 0.f, 0.f, 0.f, 0.f, 0.f};
        for (int k = 0; k < nr; ++k) {
            int s = ell[base + k];
            ushort8 v = hr8[(size_t)s * S8 + r * d8 + c];
#pragma unroll
            for (int j = 0; j < 8; ++j) a[j] += b2f(v[j]);
        }
        float dnd = dn[r * N_NODES + d];
#pragma unroll
        for (int j = 0; j < 8; ++j) acc[j] += dnd * a[j];
    }
    int f = c << 3;
#pragma unroll
    for (int j = 0; j < 8; ++j)
        acc[j] += bias[f + j] + bias[dout + f + j] + bias[2 * dout + f + j];
    if (do_relu) {
#pragma unroll
        for (int j = 0; j < 8; ++j) acc[j] = fmaxf(acc[j], 0.f);
    }
    ushort8 o;
#pragma unroll
    for (int j = 0; j < 8; ++j) o[j] = f2b(acc[j]);
    ((ushort8*)outh)[i] = o;
}

// ---------------- edge scores from UV: score = Wp2 . relu(U[s]+V[d]+bp1) + bp2 ----------
__global__ __launch_bounds__(256) void edge_score_kernel(
        const unsigned short* __restrict__ UV,
        const int* __restrict__ pos_src, const int* __restrict__ pos_dst,
        const int* __restrict__ neg_src, const int* __restrict__ neg_dst,
        const float* __restrict__ bp1, const float* __restrict__ Wp2,
        const float* __restrict__ bp2, float* __restrict__ outp) {
    __shared__ float sb[64], sw[64];
    int t = threadIdx.x;
    if (t < 64) { sb[t] = bp1[t]; sw[t] = Wp2[t]; }
    __syncthreads();
    int i = blockIdx.x * blockDim.x + t;
    if (i >= 2 * EP_EDGES) return;
    int s, d;
    if (i < EP_EDGES) { s = pos_src[i]; d = pos_dst[i]; }
    else              { s = neg_src[i - EP_EDGES]; d = neg_dst[i - EP_EDGES]; }
    const ushort8* UV8 = (const ushort8*)UV;
    float acc = bp2[0];
#pragma unroll
    for (int jv = 0; jv < 8; ++jv) {
        ushort8 u = UV8[(size_t)s * 16 + jv];
        ushort8 v = UV8[(size_t)d * 16 + 8 + jv];
#pragma unroll
        for (int j = 0; j < 8; ++j) {
            float z = b2f(u[j]) + b2f(v[j]) + sb[jv * 8 + j];
            acc = fmaf(fmaxf(z, 0.f), sw[jv * 8 + j], acc);
        }
    }
    outp[i] = acc;
}

extern "C" void kernel_launch(void* const* d_in, const int* in_sizes, int n_in,
                              void* d_out, int out_size, void* d_ws, size_t ws_size,
                              hipStream_t stream) {
    const float* x       = (const float*)d_in[0];
    const int*   rel_src = (const int*)d_in[1];
    const int*   rel_dst = (const int*)d_in[2];
    const int*   pos_src = (const int*)d_in[3];
    const int*   pos_dst = (const int*)d_in[4];
    const int*   neg_src = (const int*)d_in[5];
    const int*   neg_dst = (const int*)d_in[6];
    const float* W[4]    = {(const float*)d_in[7],  (const float*)d_in[9],
                            (const float*)d_in[11], (const float*)d_in[13]};
    const float* bias[4] = {(const float*)d_in[8],  (const float*)d_in[10],
                            (const float*)d_in[12], (const float*)d_in[14]};
    const float* Wp1 = (const float*)d_in[15];
    const float* bp1 = (const float*)d_in[16];
    const float* Wp2 = (const float*)d_in[17];
    const float* bp2 = (const float*)d_in[18];
    float* out = (float*)d_out;

    // workspace layout (bf16 buffers padded +128 rows for OOB tile reads, BM=128)
    size_t NP = (size_t)(N_NODES + 128);
    unsigned short* xb  = (unsigned short*)d_ws;          // NP x 512 (reused for UV later)
    unsigned short* h0  = xb + NP * 512;                  // NP x 512
    unsigned short* h1  = h0 + NP * 512;                  // NP x 256
    unsigned short* hr  = h1 + NP * 256;                  // N x 1536 max (fused C)
    unsigned short* Wt  = hr + (size_t)R_REL * N_NODES * 512;   // 1536*512 max
    unsigned short* But = Wt + (size_t)R_REL * 512 * 512;       // 128*64
    float* sn   = (float*)(But + 128 * 64);
    float* dn   = sn + (size_t)R_REL * N_NODES;
    int* outcnt = (int*)(dn + (size_t)R_REL * N_NODES);
    int* incnt  = outcnt + (size_t)R_REL * N_NODES;
    int* ell    = incnt + (size_t)R_REL * N_NODES;        // 3*N*32 ints
    unsigned short* UV = xb;                              // N x 128 (after layers done)

    hipMemsetAsync(outcnt, 0, sizeof(int) * 2 * R_REL * N_NODES, stream);
    count_fill_kernel<<<cdiv_h(R_REL * E_EDGES, 256), 256, 0, stream>>>(
        rel_src, rel_dst, outcnt, incnt, ell);
    norm_kernel<<<cdiv_h(R_REL * N_NODES, 256), 256, 0, stream>>>(outcnt, sn, R_REL * N_NODES);
    norm_kernel<<<cdiv_h(R_REL * N_NODES, 256), 256, 0, stream>>>(incnt, dn, R_REL * N_NODES);

    f2b8_kernel<<<cdiv_h(N_NODES * 512 / 8, 256), 256, 0, stream>>>(x, xb, N_NODES * 512 / 8);
    wp1cvt_kernel<<<cdiv_h(128 * 64, 256), 256, 0, stream>>>(Wp1, But);

    const int dims[5]  = {512, 512, 256, 128, 64};
    const int ndpad[4] = {1536, 768, 384, 256};   // 3*dout padded to x128
    unsigned short* hbufs[4] = {h0, h1, h0, h1};
    const unsigned short* hcur = xb;
    for (int l = 0; l < 4; ++l) {
        int din = dims[l], dout = dims[l + 1], NdPad = ndpad[l];
        unsigned short* hnext = hbufs[l];
        int wtot = NdPad * din;
        wcvt_kernel<<<cdiv_h(wtot, 256), 256, 0, stream>>>(W[l], Wt, din, dout, wtot);
        dim3 grid(NdPad / 128, cdiv_h(N_NODES, 128));
        gemm_bf16_fused<<<grid, 256, 0, stream>>>(hcur, Wt, hr, sn, N_NODES, din, NdPad, dout);
        int lgc = (dout == 512) ? 6 : (dout == 256) ? 5 : (dout == 128) ? 4 : 3; // log2(dout/8)
        int total = N_NODES << lgc;
        gather3_kernel<<<cdiv_h(total, 256), 256, 0, stream>>>(
            hr, NdPad / 8, dout / 8, ell, incnt, dn, bias[l], hnext, lgc, total,
            (l < 3) ? 1 : 0, dout);
        hcur = hnext;
    }

    // UV = h_final @ [Wp1_top | Wp1_bot]  (M=N, K=64, Nd=128)
    dim3 uvgrid(1, cdiv_h(N_NODES, 128));
    gemm_bf16_fused<<<uvgrid, 256, 0, stream>>>(hcur, But, UV, nullptr, N_NODES, 64, 128, 128);

    edge_score_kernel<<<cdiv_h(2 * EP_EDGES, 256), 256, 0, stream>>>(
        UV, pos_src, pos_dst, neg_src, neg_dst, bp1, Wp2, bp2, out);
}

// Round 10
// 561.584 us; speedup vs baseline: 1.5812x; 1.1012x over previous
//
#include <hip/hip_runtime.h>

#define N_NODES  50000
#define R_REL    3
#define E_EDGES  50000
#define EP_EDGES 100000
#define ELL_CAP  32

typedef __attribute__((ext_vector_type(8))) short  short8;
typedef __attribute__((ext_vector_type(8))) unsigned short ushort8;
typedef __attribute__((ext_vector_type(4))) float  floatx4;

static inline int cdiv_h(int a, int b) { return (a + b - 1) / b; }

__device__ inline unsigned short f2b(float f) {
    union { float f; unsigned u; } v; v.f = f;
    return (unsigned short)((v.u + 0x7FFF + ((v.u >> 16) & 1)) >> 16);
}
__device__ inline float b2f(unsigned short h) {
    union { unsigned u; float f; } v; v.u = ((unsigned)h) << 16;
    return v.f;
}

#define GLDS16(gp, lp) __builtin_amdgcn_global_load_lds( \
    (const __attribute__((address_space(1))) void*)(gp), \
    (__attribute__((address_space(3))) void*)(lp), 16, 0, 0)

// ---------------- degree count + ELL fill ----------------
__global__ void count_fill_kernel(const int* __restrict__ src, const int* __restrict__ dst,
                                  int* __restrict__ outcnt, int* __restrict__ incnt,
                                  int* __restrict__ ell) {
    int i = blockIdx.x * blockDim.x + threadIdx.x;
    if (i >= R_REL * E_EDGES) return;
    int r = i / E_EDGES;
    int s = src[i], d = dst[i];
    atomicAdd(&outcnt[r * N_NODES + s], 1);
    int k = atomicAdd(&incnt[r * N_NODES + d], 1);
    if (k < ELL_CAP)
        ell[((size_t)(r * N_NODES + d) << 5) + k] = s;
}

__global__ void norm_kernel(const int* __restrict__ cnt, float* __restrict__ nrm, int n) {
    int i = blockIdx.x * blockDim.x + threadIdx.x;
    if (i < n) nrm[i] = rsqrtf(fmaxf((float)cnt[i], 1.0f));
}

// ---------------- fp32 -> bf16 (8 elems/thread) ----------------
__global__ void f2b8_kernel(const float* __restrict__ in, unsigned short* __restrict__ out,
                            int total8) {
    int i = blockIdx.x * blockDim.x + threadIdx.x;
    if (i >= total8) return;
    float4 a = ((const float4*)in)[2 * i];
    float4 b = ((const float4*)in)[2 * i + 1];
    ushort8 o;
    o[0] = f2b(a.x); o[1] = f2b(a.y); o[2] = f2b(a.z); o[3] = f2b(a.w);
    o[4] = f2b(b.x); o[5] = f2b(b.y); o[6] = f2b(b.z); o[7] = f2b(b.w);
    ((ushort8*)out)[i] = o;
}

// ---------------- all weight transposes (4 layers + Wp1) in one launch ----------------
// Wt_l[nall][k] = W_l[r][k][n] with nall = r*dout+n; L3 pads rows 192..255 with 0.
__global__ void prep_weights_kernel(
        const float* __restrict__ W0, const float* __restrict__ W1,
        const float* __restrict__ W2, const float* __restrict__ W3,
        const float* __restrict__ Wp1,
        unsigned short* __restrict__ Wt0, unsigned short* __restrict__ Wt1,
        unsigned short* __restrict__ Wt2, unsigned short* __restrict__ Wt3,
        unsigned short* __restrict__ But) {
    int i = blockIdx.x * blockDim.x + threadIdx.x;
    if (i < 786432) {                       // L0: K=512 dout=512 rows=1536 (no pad)
        int k = i & 511, nall = i >> 9, r = nall >> 9, n = nall & 511;
        Wt0[i] = f2b(W0[(((size_t)r << 9) + k) * 512 + n]);
    } else if (i < 1179648) {               // L1: K=512 dout=256 rows=768
        int j = i - 786432;
        int k = j & 511, nall = j >> 9, r = nall >> 8, n = nall & 255;
        Wt1[j] = f2b(W1[(((size_t)r << 9) + k) * 256 + n]);
    } else if (i < 1277952) {               // L2: K=256 dout=128 rows=384
        int j = i - 1179648;
        int k = j & 255, nall = j >> 8, r = nall >> 7, n = nall & 127;
        Wt2[j] = f2b(W2[(((size_t)r << 8) + k) * 128 + n]);
    } else if (i < 1310720) {               // L3: K=128 dout=64 rows=256 (pad 192..255)
        int j = i - 1277952;
        int k = j & 127, nall = j >> 7, r = nall >> 6, n = nall & 63;
        Wt3[j] = (r < R_REL) ? f2b(W3[(((size_t)r << 7) + k) * 64 + n]) : (unsigned short)0;
    } else if (i < 1318912) {               // Wp1 -> But[128][64]
        int j = i - 1310720;
        int k = j & 63, jo = j >> 6, jj = jo & 63, half = jo >> 6;
        But[j] = f2b(Wp1[(size_t)(half * 64 + k) * 64 + jj]);
    }
}

// ---------------- fused MFMA GEMM: C[m][n] = (A[m][:].Bt[n][:]) * sn[n/dout][m] --------
// BM=128 BN=128 BK=64, 256 thr, 4 waves, wave tile 64x64 = 4x4 16x16 tiles.
// A+B staged in LDS (32KB) via global_load_lds; 2 barriers per 64-K step
// (half the barrier frequency of BK=32). 8-chunk XOR swizzle: LDS[r][p] holds
// global chunk p^(r&7) -> 2-way bank aliasing (free), staging reads contiguous
// 128B per 8 lanes. K%64==0, NdPad%128==0. sn==nullptr -> scale 1, no rel guard.
// XCD-locality swizzle: blocks p==j (mod 8) share one m-panel across n-blocks.
__global__ __launch_bounds__(256) void gemm_bf16_fused(
        const unsigned short* __restrict__ A, const unsigned short* __restrict__ Bt,
        unsigned short* __restrict__ C, const float* __restrict__ sn,
        int M, int K, int NdPad, int dout) {
    __shared__ unsigned short As[8192];   // [128][64]
    __shared__ unsigned short Bs[8192];   // [128][64]

    const int nN = gridDim.x, nM = gridDim.y;
    int p = blockIdx.y * nN + blockIdx.x;
    const int nig = nN << 3;
    int group = p / nig;
    int rem = p - group * nig;
    int gs = nM - (group << 3); if (gs > 8) gs = 8;
    int mb = (group << 3) + rem % gs;
    int nb = rem / gs;
    const int m0 = mb * 128, n0 = nb * 128;

    const int tid  = threadIdx.x;
    const int w    = tid >> 6;
    const int lane = tid & 63;
    const int wm   = w & 1;            // 64-row half
    const int wn   = w >> 1;           // 64-col half
    const int lrow8 = lane >> 3;       // 0..7 staging row within 8-row chunk
    const int cs    = ((lane & 7) ^ lrow8) << 3;  // swizzled src chunk offset (ushorts)

    floatx4 acc[4][4];
#pragma unroll
    for (int i = 0; i < 4; ++i)
#pragma unroll
        for (int j = 0; j < 4; ++j) acc[i][j] = (floatx4){0.f, 0.f, 0.f, 0.f};

    const int mrow  = lane & 15;
    const int phys0 = ((lane >> 4) ^ (lane & 7)) << 3;   // h=0 read offset (ushorts)
    const int phys1 = phys0 ^ 32;                        // h=1 (c_log+4 -> ^4 chunks)

    for (int k0 = 0; k0 < K; k0 += 64) {
#pragma unroll
        for (int i = 0; i < 4; ++i) {
            int rr = i * 32 + 8 * w + lrow8;
            GLDS16(A  + (size_t)(m0 + rr) * K + k0 + cs, As + (i * 32 + 8 * w) * 64);
        }
#pragma unroll
        for (int i = 0; i < 4; ++i) {
            int rr = i * 32 + 8 * w + lrow8;
            GLDS16(Bt + (size_t)(n0 + rr) * K + k0 + cs, Bs + (i * 32 + 8 * w) * 64);
        }
        __syncthreads();

#pragma unroll
        for (int h = 0; h < 2; ++h) {
            const int ph = h ? phys1 : phys0;
            short8 a[4], b[4];
#pragma unroll
            for (int nt = 0; nt < 4; ++nt)
                b[nt] = *(const short8*)&Bs[(wn * 64 + nt * 16 + mrow) * 64 + ph];
#pragma unroll
            for (int mt = 0; mt < 4; ++mt)
                a[mt] = *(const short8*)&As[(wm * 64 + mt * 16 + mrow) * 64 + ph];
#pragma unroll
            for (int mt = 0; mt < 4; ++mt)
#pragma unroll
                for (int nt = 0; nt < 4; ++nt)
                    acc[mt][nt] = __builtin_amdgcn_mfma_f32_16x16x32_bf16(a[mt], b[nt],
                                                                          acc[mt][nt], 0, 0, 0);
        }
        __syncthreads();
    }

    // epilogue: C/D layout col=lane&15, row=(lane>>4)*4+reg
    const int colb = n0 + wn * 64;
    const int r_quad = colb / dout;          // relation of this 64-col quadrant
    if (sn && r_quad >= R_REL) return;       // zero-pad columns: skip store
    const int col = colb + (lane & 15);
    const int rb0 = m0 + wm * 64 + (lane >> 4) * 4;
#pragma unroll
    for (int mt = 0; mt < 4; ++mt) {
#pragma unroll
        for (int reg = 0; reg < 4; ++reg) {
            int row = rb0 + mt * 16 + reg;
            if (row < M) {
                float rs = sn ? sn[(size_t)r_quad * N_NODES + row] : 1.0f;
#pragma unroll
                for (int nt = 0; nt < 4; ++nt)
                    C[(size_t)row * NdPad + col + nt * 16] = f2b(acc[mt][nt][reg] * rs);
            }
        }
    }
}

// ---------------- fused 3-relation ELL gather + bias-sum + optional ReLU ----------------
// hr rows are [rel0 | rel1 | rel2 | pad] with row stride S8 ushort8-chunks.
__global__ void gather3_kernel(const unsigned short* __restrict__ hr, int S8, int d8,
                               const int* __restrict__ ell, const int* __restrict__ incnt,
                               const float* __restrict__ dn, const float* __restrict__ bias,
                               unsigned short* __restrict__ outh,
                               int lgc, int total, int do_relu, int dout) {
    int i = blockIdx.x * blockDim.x + threadIdx.x;
    if (i >= total) return;
    int d = i >> lgc;
    int c = i & ((1 << lgc) - 1);
    float acc[8] = {0.f, 0.f, 0.f, 0.f, 0.f, 0.f, 0.f, 0.f};
    const ushort8* hr8 = (const ushort8*)hr;
#pragma unroll
    for (int r = 0; r < R_REL; ++r) {
        int nr = incnt[r * N_NODES + d];
        nr = nr < ELL_CAP ? nr : ELL_CAP;
        size_t base = (size_t)(r * N_NODES + d) << 5;
        float a[8] = {0.f, 0.f, 0.f, 0.f, 0.f, 0.f, 0.f, 0.f};
        for (int k = 0; k < nr; ++k) {
            int s = ell[base + k];
            ushort8 v = hr8[(size_t)s * S8 + r * d8 + c];
#pragma unroll
            for (int j = 0; j < 8; ++j) a[j] += b2f(v[j]);
        }
        float dnd = dn[r * N_NODES + d];
#pragma unroll
        for (int j = 0; j < 8; ++j) acc[j] += dnd * a[j];
    }
    int f = c << 3;
#pragma unroll
    for (int j = 0; j < 8; ++j)
        acc[j] += bias[f + j] + bias[dout + f + j] + bias[2 * dout + f + j];
    if (do_relu) {
#pragma unroll
        for (int j = 0; j < 8; ++j) acc[j] = fmaxf(acc[j], 0.f);
    }
    ushort8 o;
#pragma unroll
    for (int j = 0; j < 8; ++j) o[j] = f2b(acc[j]);
    ((ushort8*)outh)[i] = o;
}

// ---------------- edge scores from UV: score = Wp2 . relu(U[s]+V[d]+bp1) + bp2 ----------
__global__ __launch_bounds__(256) void edge_score_kernel(
        const unsigned short* __restrict__ UV,
        const int* __restrict__ pos_src, const int* __restrict__ pos_dst,
        const int* __restrict__ neg_src, const int* __restrict__ neg_dst,
        const float* __restrict__ bp1, const float* __restrict__ Wp2,
        const float* __restrict__ bp2, float* __restrict__ outp) {
    __shared__ float sb[64], sw[64];
    int t = threadIdx.x;
    if (t < 64) { sb[t] = bp1[t]; sw[t] = Wp2[t]; }
    __syncthreads();
    int i = blockIdx.x * blockDim.x + t;
    if (i >= 2 * EP_EDGES) return;
    int s, d;
    if (i < EP_EDGES) { s = pos_src[i]; d = pos_dst[i]; }
    else              { s = neg_src[i - EP_EDGES]; d = neg_dst[i - EP_EDGES]; }
    const ushort8* UV8 = (const ushort8*)UV;
    float acc = bp2[0];
#pragma unroll
    for (int jv = 0; jv < 8; ++jv) {
        ushort8 u = UV8[(size_t)s * 16 + jv];
        ushort8 v = UV8[(size_t)d * 16 + 8 + jv];
#pragma unroll
        for (int j = 0; j < 8; ++j) {
            float z = b2f(u[j]) + b2f(v[j]) + sb[jv * 8 + j];
            acc = fmaf(fmaxf(z, 0.f), sw[jv * 8 + j], acc);
        }
    }
    outp[i] = acc;
}

extern "C" void kernel_launch(void* const* d_in, const int* in_sizes, int n_in,
                              void* d_out, int out_size, void* d_ws, size_t ws_size,
                              hipStream_t stream) {
    const float* x       = (const float*)d_in[0];
    const int*   rel_src = (const int*)d_in[1];
    const int*   rel_dst = (const int*)d_in[2];
    const int*   pos_src = (const int*)d_in[3];
    const int*   pos_dst = (const int*)d_in[4];
    const int*   neg_src = (const int*)d_in[5];
    const int*   neg_dst = (const int*)d_in[6];
    const float* W[4]    = {(const float*)d_in[7],  (const float*)d_in[9],
                            (const float*)d_in[11], (const float*)d_in[13]};
    const float* bias[4] = {(const float*)d_in[8],  (const float*)d_in[10],
                            (const float*)d_in[12], (const float*)d_in[14]};
    const float* Wp1 = (const float*)d_in[15];
    const float* bp1 = (const float*)d_in[16];
    const float* Wp2 = (const float*)d_in[17];
    const float* bp2 = (const float*)d_in[18];
    float* out = (float*)d_out;

    // workspace layout (bf16 buffers padded +128 rows for OOB tile reads, BM=128)
    size_t NP = (size_t)(N_NODES + 128);
    unsigned short* xb  = (unsigned short*)d_ws;          // NP x 512 (reused for UV later)
    unsigned short* h0  = xb + NP * 512;                  // NP x 512
    unsigned short* h1  = h0 + NP * 512;                  // NP x 256
    unsigned short* hr  = h1 + NP * 256;                  // N x 1536 max (fused C)
    unsigned short* Wt0 = hr + (size_t)R_REL * N_NODES * 512;
    unsigned short* Wt1 = Wt0 + 786432;
    unsigned short* Wt2 = Wt1 + 393216;
    unsigned short* Wt3 = Wt2 + 98304;
    unsigned short* But = Wt3 + 32768;                    // 128*64
    float* sn   = (float*)(But + 128 * 64);
    float* dn   = sn + (size_t)R_REL * N_NODES;
    int* outcnt = (int*)(dn + (size_t)R_REL * N_NODES);
    int* incnt  = outcnt + (size_t)R_REL * N_NODES;
    int* ell    = incnt + (size_t)R_REL * N_NODES;        // 3*N*32 ints
    unsigned short* UV = xb;                              // N x 128 (after layers done)
    const unsigned short* Wt[4] = {Wt0, Wt1, Wt2, Wt3};

    hipMemsetAsync(outcnt, 0, sizeof(int) * 2 * R_REL * N_NODES, stream);
    count_fill_kernel<<<cdiv_h(R_REL * E_EDGES, 256), 256, 0, stream>>>(
        rel_src, rel_dst, outcnt, incnt, ell);
    // sn,dn contiguous and outcnt,incnt contiguous -> one launch covers both
    norm_kernel<<<cdiv_h(2 * R_REL * N_NODES, 256), 256, 0, stream>>>(
        outcnt, sn, 2 * R_REL * N_NODES);

    f2b8_kernel<<<cdiv_h(N_NODES * 512 / 8, 256), 256, 0, stream>>>(x, xb, N_NODES * 512 / 8);
    prep_weights_kernel<<<cdiv_h(1318912, 256), 256, 0, stream>>>(
        W[0], W[1], W[2], W[3], Wp1, Wt0, Wt1, Wt2, Wt3, But);

    const int dims[5]  = {512, 512, 256, 128, 64};
    const int ndpad[4] = {1536, 768, 384, 256};   // 3*dout padded to x128
    unsigned short* hbufs[4] = {h0, h1, h0, h1};
    const unsigned short* hcur = xb;
    for (int l = 0; l < 4; ++l) {
        int din = dims[l], dout = dims[l + 1], NdPad = ndpad[l];
        unsigned short* hnext = hbufs[l];
        dim3 grid(NdPad / 128, cdiv_h(N_NODES, 128));
        gemm_bf16_fused<<<grid, 256, 0, stream>>>(hcur, Wt[l], hr, sn, N_NODES, din, NdPad, dout);
        int lgc = (dout == 512) ? 6 : (dout == 256) ? 5 : (dout == 128) ? 4 : 3; // log2(dout/8)
        int total = N_NODES << lgc;
        gather3_kernel<<<cdiv_h(total, 256), 256, 0, stream>>>(
            hr, NdPad / 8, dout / 8, ell, incnt, dn, bias[l], hnext, lgc, total,
            (l < 3) ? 1 : 0, dout);
        hcur = hnext;
    }

    // UV = h_final @ [Wp1_top | Wp1_bot]  (M=N, K=64, Nd=128)
    dim3 uvgrid(1, cdiv_h(N_NODES, 128));
    gemm_bf16_fused<<<uvgrid, 256, 0, stream>>>(hcur, But, UV, nullptr, N_NODES, 64, 128, 128);

    edge_score_kernel<<<cdiv_h(2 * EP_EDGES, 256), 256, 0, stream>>>(
        UV, pos_src, pos_dst, neg_src, neg_dst, bp1, Wp2, bp2, out);
}